// Round 1
// baseline (11785.374 us; speedup 1.0000x reference)
//
#include <hip/hip_runtime.h>

// Problem constants (AttentionSpeller): T=128, B=32, E=H=512, U=1024, V=10000
#define T_STEPS 128
#define BATCH   32
#define HID     512
#define EMB     512
#define ULEN    1024
#define VOCAB   10000
#define G4H     2048   // 4*H

static inline int cdiv(int a, int b) { return (a + b - 1) / b; }

// ---------------------------------------------------------------------------
// Generic tiled fp32 GEMM: C[M,N] = A[M,K] * op(B) (+ bias[N])
//   TRANSB=true : B is [N,K] row-major (C = A * B^T)  — K contiguous in both
//   TRANSB=false: B is [K,N] row-major (C = A * B)
// Batched via blockIdx.z with element strides sA/sB/sC.
// Assumes: M % 64 == 0, K % 16 == 0, K % 4 == 0. N guarded (for V=10000).
// ---------------------------------------------------------------------------
template <bool TRANSB>
__global__ __launch_bounds__(256)
void gemm_f32(const float* __restrict__ A, long lda, long sA,
              const float* __restrict__ Bm, long ldb, long sB,
              float* __restrict__ C, long ldc, long sC,
              int M, int N, int K, const float* __restrict__ bias)
{
    __shared__ float As[16][68];
    __shared__ float Bs[16][68];
    const int bz = blockIdx.z;
    A  += (size_t)bz * sA;
    Bm += (size_t)bz * sB;
    C  += (size_t)bz * sC;
    const int m0 = blockIdx.y * 64;
    const int n0 = blockIdx.x * 64;
    const int tid = threadIdx.x;
    const int tx = tid & 15, ty = tid >> 4;
    const int lr = tid >> 2;          // 0..63: tile row
    const int lk = (tid & 3) * 4;     // 0,4,8,12: k offset

    float acc[4][4] = {{0.f}};

    for (int k0 = 0; k0 < K; k0 += 16) {
        // A tile (M is always a multiple of 64 here -> no row guard)
        float4 av = *(const float4*)(A + (size_t)(m0 + lr) * lda + (k0 + lk));
        As[lk + 0][lr] = av.x; As[lk + 1][lr] = av.y;
        As[lk + 2][lr] = av.z; As[lk + 3][lr] = av.w;
        if (TRANSB) {
            const int nr = n0 + lr;
            float4 bv = make_float4(0.f, 0.f, 0.f, 0.f);
            if (nr < N) bv = *(const float4*)(Bm + (size_t)nr * ldb + (k0 + lk));
            Bs[lk + 0][lr] = bv.x; Bs[lk + 1][lr] = bv.y;
            Bs[lk + 2][lr] = bv.z; Bs[lk + 3][lr] = bv.w;
        } else {
            const int kr = tid >> 4;          // 0..15
            const int nc = (tid & 15) * 4;    // 0..60
            float4 bv = make_float4(0.f, 0.f, 0.f, 0.f);
            if (n0 + nc < N) bv = *(const float4*)(Bm + (size_t)(k0 + kr) * ldb + (n0 + nc));
            *(float4*)&Bs[kr][nc] = bv;
        }
        __syncthreads();
#pragma unroll
        for (int kk = 0; kk < 16; ++kk) {
            float ar[4], br[4];
#pragma unroll
            for (int i = 0; i < 4; i++) ar[i] = As[kk][ty * 4 + i];
#pragma unroll
            for (int j = 0; j < 4; j++) br[j] = Bs[kk][tx * 4 + j];
#pragma unroll
            for (int i = 0; i < 4; i++)
#pragma unroll
                for (int j = 0; j < 4; j++)
                    acc[i][j] += ar[i] * br[j];
        }
        __syncthreads();
    }
#pragma unroll
    for (int i = 0; i < 4; i++) {
        const int row = m0 + ty * 4 + i;
#pragma unroll
        for (int j = 0; j < 4; j++) {
            const int col = n0 + tx * 4 + j;
            if (col < N) {
                float v = acc[i][j];
                if (bias) v += bias[col];
                C[(size_t)row * ldc + col] = v;
            }
        }
    }
}

// ---------------------------------------------------------------------------
// Persistent LSTM scan (one layer, all T steps). Grid MUST be 256 blocks
// (<= 256 CUs, tiny LDS/VGPR -> all co-resident; one grid barrier per step).
// Block bid owns h-slice {2*bid, 2*bid+1}: computes the 8 gate columns
// {g*512 + 2*bid + j} for all 32 batch rows (1 output/thread, K=512 dot),
// then threads 0..63 apply the cell (c-state lives in registers) and write
// h to h_all[t] (double-buffered through t -> fresh addresses every step).
// ---------------------------------------------------------------------------
__device__ inline float sigmoidf_(float x) { return 1.f / (1.f + expf(-x)); }

__global__ __launch_bounds__(256)
void lstm_scan(const float* __restrict__ gp,    // (T*B*2048) x@W_ih^T + b_ih + b_hh
               const float* __restrict__ Whh,   // (2048 x 512) row-major
               const float* __restrict__ h0,    // (B*H) layer slice
               const float* __restrict__ c0,    // (B*H) layer slice
               float* __restrict__ h_all,       // (T*B*H) out
               unsigned* __restrict__ cnt)      // zeroed barrier counter
{
    __shared__ float glds[256];
    const int tid = threadIdx.x;
    const int b   = tid & 31;
    const int c6  = tid >> 5;          // 0..7
    const int g   = c6 >> 1, j = c6 & 1;
    const int hbase = blockIdx.x * 2;
    const int n   = g * 512 + hbase + j;
    const float* Wrow = Whh + (size_t)n * HID;

    float c_state = 0.f;
    if (tid < 64) c_state = c0[b * HID + hbase + (tid >> 5)];

    unsigned target = gridDim.x;
    for (int t = 0; t < T_STEPS; ++t) {
        const float* hrow = ((t == 0) ? h0 : (h_all + (size_t)(t - 1) * BATCH * HID)) + b * HID;
        float s0 = 0.f, s1 = 0.f, s2 = 0.f, s3 = 0.f;
#pragma unroll 4
        for (int k = 0; k < HID; k += 8) {
            float4 ha = *(const float4*)(hrow + k);
            float4 hb = *(const float4*)(hrow + k + 4);
            float4 wa = *(const float4*)(Wrow + k);
            float4 wb = *(const float4*)(Wrow + k + 4);
            s0 += ha.x * wa.x + ha.y * wa.y;
            s1 += ha.z * wa.z + ha.w * wa.w;
            s2 += hb.x * wb.x + hb.y * wb.y;
            s3 += hb.z * wb.z + hb.w * wb.w;
        }
        float acc = gp[((size_t)t * BATCH + b) * G4H + n] + ((s0 + s1) + (s2 + s3));
        glds[c6 * 32 + b] = acc;
        __syncthreads();
        if (tid < 64) {
            const int jc = tid >> 5;
            float iv = sigmoidf_(glds[(0 + jc) * 32 + b]);
            float fv = sigmoidf_(glds[(2 + jc) * 32 + b]);
            float gv = tanhf    (glds[(4 + jc) * 32 + b]);
            float ov = sigmoidf_(glds[(6 + jc) * 32 + b]);
            c_state = fv * c_state + iv * gv;
            float hn = ov * tanhf(c_state);
            h_all[((size_t)t * BATCH + b) * HID + hbase + jc] = hn;
            __threadfence();   // agent-scope release of h stores (cross-XCD)
        }
        __syncthreads();       // drains each thread's stores (vmcnt) before barrier
        if (tid == 0) {
            atomicAdd(cnt, 1u);   // device-scope by default
            while (__hip_atomic_load(cnt, __ATOMIC_RELAXED, __HIP_MEMORY_SCOPE_AGENT) < target)
                __builtin_amdgcn_s_sleep(1);
            __threadfence();   // acquire: invalidate L1/L2 before next step's h reads
        }
        __syncthreads();
        target += gridDim.x;
    }
}

// ---------------------------------------------------------------------------
// Softmax over U=1024 (attention weights), in place. One block per (t,b) row.
// ---------------------------------------------------------------------------
__device__ inline float warpReduceMax_(float v) {
#pragma unroll
    for (int o = 32; o > 0; o >>= 1) v = fmaxf(v, __shfl_xor(v, o));
    return v;
}
__device__ inline float warpReduceSum_(float v) {
#pragma unroll
    for (int o = 32; o > 0; o >>= 1) v += __shfl_xor(v, o);
    return v;
}
__device__ inline float blockReduceMax_(float v, float* red) {
    v = warpReduceMax_(v);
    if ((threadIdx.x & 63) == 0) red[threadIdx.x >> 6] = v;
    __syncthreads();
    float r = fmaxf(fmaxf(red[0], red[1]), fmaxf(red[2], red[3]));
    __syncthreads();
    return r;
}
__device__ inline float blockReduceSum_(float v, float* red) {
    v = warpReduceSum_(v);
    if ((threadIdx.x & 63) == 0) red[threadIdx.x >> 6] = v;
    __syncthreads();
    float r = (red[0] + red[1]) + (red[2] + red[3]);
    __syncthreads();
    return r;
}

__global__ __launch_bounds__(256)
void softmax_u(float* __restrict__ s)
{
    __shared__ float red[4];
    float4* p = (float4*)(s + (size_t)blockIdx.x * ULEN);
    float4 v = p[threadIdx.x];
    float mx = fmaxf(fmaxf(v.x, v.y), fmaxf(v.z, v.w));
    mx = blockReduceMax_(mx, red);
    v.x = expf(v.x - mx); v.y = expf(v.y - mx);
    v.z = expf(v.z - mx); v.w = expf(v.w - mx);
    float sm = blockReduceSum_(v.x + v.y + v.z + v.w, red);
    float inv = 1.f / sm;
    v.x *= inv; v.y *= inv; v.z *= inv; v.w *= inv;
    p[threadIdx.x] = v;
}

// ---------------------------------------------------------------------------
// Softmax over V=10000 (output), in place. One block per (t,b) row; the row
// is staged in LDS (40 KB) so global is read once + written once.
// ---------------------------------------------------------------------------
__global__ __launch_bounds__(256)
void softmax_v(float* __restrict__ out)
{
    __shared__ float buf[VOCAB];
    __shared__ float red[4];
    float* p = out + (size_t)blockIdx.x * VOCAB;
    float mx = -INFINITY;
    for (int i = threadIdx.x; i < VOCAB; i += 256) {
        float x = p[i]; buf[i] = x; mx = fmaxf(mx, x);
    }
    mx = blockReduceMax_(mx, red);
    float sm = 0.f;
    for (int i = threadIdx.x; i < VOCAB; i += 256) {
        float e = expf(buf[i] - mx); buf[i] = e; sm += e;
    }
    sm = blockReduceSum_(sm, red);
    float inv = 1.f / sm;
    for (int i = threadIdx.x; i < VOCAB; i += 256) p[i] = buf[i] * inv;
}

// ---------------------------------------------------------------------------
// Prep: combined biases (b_ih + b_hh) and zeroed barrier counters (ws is
// poisoned 0xAA before every call, so counters must be re-zeroed each call).
// ---------------------------------------------------------------------------
__global__ void prep(const float* __restrict__ bi1, const float* __restrict__ bh1,
                     const float* __restrict__ bi2, const float* __restrict__ bh2,
                     float* __restrict__ bias1, float* __restrict__ bias2,
                     unsigned* __restrict__ cnts)
{
    int i = blockIdx.x * 256 + threadIdx.x;
    if (i < G4H) { bias1[i] = bi1[i] + bh1[i]; bias2[i] = bi2[i] + bh2[i]; }
    if (i < 8) cnts[i] = 0u;
}

// ---------------------------------------------------------------------------
extern "C" void kernel_launch(void* const* d_in, const int* in_sizes, int n_in,
                              void* d_out, int out_size, void* d_ws, size_t ws_size,
                              hipStream_t stream)
{
    const float* inputs = (const float*)d_in[0];   // (T,B,E)
    const float* h0     = (const float*)d_in[1];   // (2,B,H)
    const float* c0     = (const float*)d_in[2];   // (2,B,H)
    const float* L      = (const float*)d_in[3];   // (U,B,H)
    const float* W_ih1  = (const float*)d_in[4];   // (4H,E)
    const float* W_hh1  = (const float*)d_in[5];   // (4H,H)
    const float* b_ih1  = (const float*)d_in[6];
    const float* b_hh1  = (const float*)d_in[7];
    const float* W_ih2  = (const float*)d_in[8];   // (4H,H)
    const float* W_hh2  = (const float*)d_in[9];   // (4H,H)
    const float* b_ih2  = (const float*)d_in[10];
    const float* b_hh2  = (const float*)d_in[11];
    const float* W_out  = (const float*)d_in[12];  // (V,H)
    const float* b_out  = (const float*)d_in[13];  // (V)
    float* out = (float*)d_out;                    // (T,B,V) fp32

    // Workspace layout (~59 MB total; scores aliases the dead pre-gates buf)
    float* ws    = (float*)d_ws;
    float* gates = ws;                                        // T*B*4H = 8,388,608 f
    float* h1    = gates + (size_t)T_STEPS * BATCH * G4H;     // T*B*H
    float* h2    = h1    + (size_t)T_STEPS * BATCH * HID;     // T*B*H
    float* ctx   = h2    + (size_t)T_STEPS * BATCH * HID;     // T*B*H
    float* bias1 = ctx   + (size_t)T_STEPS * BATCH * HID;     // 4H
    float* bias2 = bias1 + G4H;                               // 4H
    unsigned* cnts = (unsigned*)(bias2 + G4H);                // barrier counters
    float* scores = gates;                                    // alias (T,B,U)

    prep<<<8, 256, 0, stream>>>(b_ih1, b_hh1, b_ih2, b_hh2, bias1, bias2, cnts);

    // X1 = inputs @ W_ih1^T + (b_ih1+b_hh1)   [4096 x 2048 x 512]
    gemm_f32<true><<<dim3(G4H / 64, (T_STEPS * BATCH) / 64, 1), 256, 0, stream>>>(
        inputs, EMB, 0, W_ih1, EMB, 0, gates, G4H, 0,
        T_STEPS * BATCH, G4H, EMB, bias1);

    // Layer-1 scan -> h1_all
    lstm_scan<<<256, 256, 0, stream>>>(gates, W_hh1, h0, c0, h1, cnts + 0);

    // scores[t,b,u] = h1[t,b,:] . L[u,b,:]   batched over b (NT GEMM)
    gemm_f32<true><<<dim3(ULEN / 64, T_STEPS / 64, BATCH), 256, 0, stream>>>(
        h1, (long)BATCH * HID, HID,
        L,  (long)BATCH * HID, HID,
        scores, (long)BATCH * ULEN, ULEN,
        T_STEPS, ULEN, HID, nullptr);

    softmax_u<<<T_STEPS * BATCH, 256, 0, stream>>>(scores);

    // ctx[t,b,h] = sum_u w[t,b,u] * L[u,b,h]  batched over b (NN GEMM, K=U)
    gemm_f32<false><<<dim3(HID / 64, T_STEPS / 64, BATCH), 256, 0, stream>>>(
        scores, (long)BATCH * ULEN, ULEN,
        L,      (long)BATCH * HID,  HID,
        ctx,    (long)BATCH * HID,  HID,
        T_STEPS, HID, ULEN, nullptr);

    // X2 = ctx @ W_ih2^T + (b_ih2+b_hh2)   [4096 x 2048 x 512] (reuses gates buf)
    gemm_f32<true><<<dim3(G4H / 64, (T_STEPS * BATCH) / 64, 1), 256, 0, stream>>>(
        ctx, HID, 0, W_ih2, HID, 0, gates, G4H, 0,
        T_STEPS * BATCH, G4H, HID, bias2);

    // Layer-2 scan -> h2_all
    lstm_scan<<<256, 256, 0, stream>>>(gates, W_hh2, h0 + BATCH * HID, c0 + BATCH * HID,
                                       h2, cnts + 1);

    // logits = h2 @ W_out^T + b_out   [4096 x 10000 x 512] -> d_out
    gemm_f32<true><<<dim3(cdiv(VOCAB, 64), (T_STEPS * BATCH) / 64, 1), 256, 0, stream>>>(
        h2, HID, 0, W_out, HID, 0, out, VOCAB, 0,
        T_STEPS * BATCH, VOCAB, HID, b_out);

    softmax_v<<<T_STEPS * BATCH, 256, 0, stream>>>(out);
}

// Round 2
// 9814.447 us; speedup vs baseline: 1.2008x; 1.2008x over previous
//
#include <hip/hip_runtime.h>

// Problem constants (AttentionSpeller): T=128, B=32, E=H=512, U=1024, V=10000
#define T_STEPS 128
#define BATCH   32
#define HID     512
#define EMB     512
#define ULEN    1024
#define VOCAB   10000
#define G4H     2048   // 4*H

static inline int cdiv(int a, int b) { return (a + b - 1) / b; }

// ---------------------------------------------------------------------------
// Generic tiled fp32 GEMM: C[M,N] = A[M,K] * op(B) (+ bias[N])
//   TRANSB=true : B is [N,K] row-major (C = A * B^T)  — K contiguous in both
//   TRANSB=false: B is [K,N] row-major (C = A * B)
// Batched via blockIdx.z with element strides sA/sB/sC.
// Assumes: M % 64 == 0, K % 16 == 0. N guarded (for V=10000).
// ---------------------------------------------------------------------------
template <bool TRANSB>
__global__ __launch_bounds__(256)
void gemm_f32(const float* __restrict__ A, long lda, long sA,
              const float* __restrict__ Bm, long ldb, long sB,
              float* __restrict__ C, long ldc, long sC,
              int M, int N, int K, const float* __restrict__ bias)
{
    __shared__ float As[16][68];
    __shared__ float Bs[16][68];
    const int bz = blockIdx.z;
    A  += (size_t)bz * sA;
    Bm += (size_t)bz * sB;
    C  += (size_t)bz * sC;
    const int m0 = blockIdx.y * 64;
    const int n0 = blockIdx.x * 64;
    const int tid = threadIdx.x;
    const int tx = tid & 15, ty = tid >> 4;
    const int lr = tid >> 2;          // 0..63: tile row
    const int lk = (tid & 3) * 4;     // 0,4,8,12: k offset

    float acc[4][4] = {{0.f}};

    for (int k0 = 0; k0 < K; k0 += 16) {
        float4 av = *(const float4*)(A + (size_t)(m0 + lr) * lda + (k0 + lk));
        As[lk + 0][lr] = av.x; As[lk + 1][lr] = av.y;
        As[lk + 2][lr] = av.z; As[lk + 3][lr] = av.w;
        if (TRANSB) {
            const int nr = n0 + lr;
            float4 bv = make_float4(0.f, 0.f, 0.f, 0.f);
            if (nr < N) bv = *(const float4*)(Bm + (size_t)nr * ldb + (k0 + lk));
            Bs[lk + 0][lr] = bv.x; Bs[lk + 1][lr] = bv.y;
            Bs[lk + 2][lr] = bv.z; Bs[lk + 3][lr] = bv.w;
        } else {
            const int kr = tid >> 4;          // 0..15
            const int nc = (tid & 15) * 4;    // 0..60
            float4 bv = make_float4(0.f, 0.f, 0.f, 0.f);
            if (n0 + nc < N) bv = *(const float4*)(Bm + (size_t)(k0 + kr) * ldb + (n0 + nc));
            *(float4*)&Bs[kr][nc] = bv;
        }
        __syncthreads();
#pragma unroll
        for (int kk = 0; kk < 16; ++kk) {
            float ar[4], br[4];
#pragma unroll
            for (int i = 0; i < 4; i++) ar[i] = As[kk][ty * 4 + i];
#pragma unroll
            for (int j = 0; j < 4; j++) br[j] = Bs[kk][tx * 4 + j];
#pragma unroll
            for (int i = 0; i < 4; i++)
#pragma unroll
                for (int j = 0; j < 4; j++)
                    acc[i][j] += ar[i] * br[j];
        }
        __syncthreads();
    }
#pragma unroll
    for (int i = 0; i < 4; i++) {
        const int row = m0 + ty * 4 + i;
#pragma unroll
        for (int j = 0; j < 4; j++) {
            const int col = n0 + tx * 4 + j;
            if (col < N) {
                float v = acc[i][j];
                if (bias) v += bias[col];
                C[(size_t)row * ldc + col] = v;
            }
        }
    }
}

// ---------------------------------------------------------------------------
// Persistent LSTM scan v2 — fence-free coherence.
//
// 256 blocks (1/CU), 256 threads. Block bid owns h columns {2bid, 2bid+1},
// i.e. gate columns n = g*512 + 2bid + j (4 gates x 2 j).
// Thread layout: tid = b*8 + n_local  (b in 0..31, n_local in 0..7).
//   -> within a wave, 8 lanes share each h row (LDS same-addr broadcast, free)
//      and 8 lanes share each W row (global same-line coalesce).
//
// Coherence WITHOUT __threadfence (which on gfx950 = per-step L2 wb/inv, the
// round-0 disaster: 41us/step, W_hh evicted every step):
//   - h(t) stores + h(t-1) loads use relaxed AGENT-scope atomics (sc1 path,
//     coherent at L3; bypasses stale per-XCD L2 / per-CU L1).
//   - __syncthreads() drains vmcnt(0) before the barrier atomicAdd, ordering
//     the sc1 stores before the counter increment. No cache invalidation ->
//     W_hh stays hot in L1/L2 across all 128 steps.
// h(t-1) is staged to LDS once per block per step (64KB, XOR-swizzled by
// (b&7) so the 8 distinct rows read per wave-cycle hit distinct banks).
// Gate i/f/g/o exchange via __shfl within 8-lane groups; c-state in registers.
// ---------------------------------------------------------------------------
__device__ inline float sigmoidf_(float x) { return 1.f / (1.f + expf(-x)); }

__global__ __launch_bounds__(256)
void lstm_scan(const float* __restrict__ gp,    // (T*B*2048) x@W_ih^T + b_ih + b_hh
               const float* __restrict__ Whh,   // (2048 x 512) row-major
               const float* __restrict__ h0,    // (B*H) layer slice
               const float* __restrict__ c0,    // (B*H) layer slice
               float* __restrict__ h_all,       // (T*B*H) out
               unsigned* __restrict__ cnt)      // zeroed barrier counter
{
    __shared__ float h_lds[BATCH * HID];        // 64 KB exactly, swizzled
    const int tid  = threadIdx.x;
    const int lane = tid & 63;
    const int b    = tid >> 3;                  // 0..31
    const int nl   = tid & 7;                   // 0..7
    const int g    = nl >> 1, j = nl & 1;
    const int hbase = blockIdx.x * 2;
    const int n    = (g << 9) + hbase + j;      // gate column 0..2047
    const float* __restrict__ Wrow = Whh + (size_t)n * HID;
    const int swz  = (b & 7) << 2;
    const int sbase = lane & ~7;                // shuffle group base lane

    float c_state = (nl < 2) ? c0[b * HID + hbase + j] : 0.f;

    unsigned target = 256;
    for (int t = 0; t < T_STEPS; ++t) {
        // issue the (h-independent) gate preactivation load early
        float gval = gp[((size_t)t * BATCH + b) * G4H + n];

        // ---- stage h(t-1) -> LDS via coherent (agent/sc1) loads ----
        const float* hsrc = (t == 0) ? h0 : (h_all + (size_t)(t - 1) * BATCH * HID);
#pragma unroll
        for (int i = 0; i < 64; ++i) {
            const int flat = i * 256 + tid;                 // coalesced
            float v = __hip_atomic_load(hsrc + flat, __ATOMIC_RELAXED,
                                        __HIP_MEMORY_SCOPE_AGENT);
            const int bb = flat >> 9, kk = flat & 511;
            h_lds[(bb << 9) + (kk ^ ((bb & 7) << 2))] = v;
        }
        __syncthreads();

        // ---- dot: acc = gp + h(t-1) . Wrow  (h from LDS, W from L1) ----
        const float* hrow = &h_lds[b << 9];
        float s0 = 0.f, s1 = 0.f, s2 = 0.f, s3 = 0.f;
#pragma unroll 4
        for (int k = 0; k < HID; k += 8) {
            const int i1 = k ^ swz;
            float4 ha = *(const float4*)(hrow + i1);
            float4 hb = *(const float4*)(hrow + (i1 ^ 4));
            float4 wa = *(const float4*)(Wrow + k);
            float4 wb = *(const float4*)(Wrow + k + 4);
            s0 += ha.x * wa.x + ha.y * wa.y;
            s1 += ha.z * wa.z + ha.w * wa.w;
            s2 += hb.x * wb.x + hb.y * wb.y;
            s3 += hb.z * wb.z + hb.w * wb.w;
        }
        float acc = gval + ((s0 + s1) + (s2 + s3));

        // ---- cell: exchange f/g/o via shuffles; owners nl in {0,1} ----
        float fva = __shfl(acc, sbase + 2 + j);
        float gva = __shfl(acc, sbase + 4 + j);
        float ova = __shfl(acc, sbase + 6 + j);
        if (nl < 2) {
            float iv = sigmoidf_(acc);
            float fv = sigmoidf_(fva);
            float gv = tanhf(gva);
            float ov = sigmoidf_(ova);
            c_state = fv * c_state + iv * gv;
            float hn = ov * tanhf(c_state);
            __hip_atomic_store(h_all + ((size_t)t * BATCH + b) * HID + hbase + j,
                               hn, __ATOMIC_RELAXED, __HIP_MEMORY_SCOPE_AGENT);
        }

        // ---- grid barrier (fence-free; syncthreads drains vmcnt first) ----
        __syncthreads();
        if (tid == 0) {
            atomicAdd(cnt, 1u);   // device-scope by default
            while (__hip_atomic_load(cnt, __ATOMIC_RELAXED, __HIP_MEMORY_SCOPE_AGENT) < target)
                __builtin_amdgcn_s_sleep(2);
        }
        __syncthreads();
        target += 256;
    }
}

// ---------------------------------------------------------------------------
// Softmax over U=1024 (attention weights), in place. One block per (t,b) row.
// ---------------------------------------------------------------------------
__device__ inline float warpReduceMax_(float v) {
#pragma unroll
    for (int o = 32; o > 0; o >>= 1) v = fmaxf(v, __shfl_xor(v, o));
    return v;
}
__device__ inline float warpReduceSum_(float v) {
#pragma unroll
    for (int o = 32; o > 0; o >>= 1) v += __shfl_xor(v, o);
    return v;
}
__device__ inline float blockReduceMax_(float v, float* red) {
    v = warpReduceMax_(v);
    if ((threadIdx.x & 63) == 0) red[threadIdx.x >> 6] = v;
    __syncthreads();
    float r = fmaxf(fmaxf(red[0], red[1]), fmaxf(red[2], red[3]));
    __syncthreads();
    return r;
}
__device__ inline float blockReduceSum_(float v, float* red) {
    v = warpReduceSum_(v);
    if ((threadIdx.x & 63) == 0) red[threadIdx.x >> 6] = v;
    __syncthreads();
    float r = (red[0] + red[1]) + (red[2] + red[3]);
    __syncthreads();
    return r;
}

__global__ __launch_bounds__(256)
void softmax_u(float* __restrict__ s)
{
    __shared__ float red[4];
    float4* p = (float4*)(s + (size_t)blockIdx.x * ULEN);
    float4 v = p[threadIdx.x];
    float mx = fmaxf(fmaxf(v.x, v.y), fmaxf(v.z, v.w));
    mx = blockReduceMax_(mx, red);
    v.x = expf(v.x - mx); v.y = expf(v.y - mx);
    v.z = expf(v.z - mx); v.w = expf(v.w - mx);
    float sm = blockReduceSum_(v.x + v.y + v.z + v.w, red);
    float inv = 1.f / sm;
    v.x *= inv; v.y *= inv; v.z *= inv; v.w *= inv;
    p[threadIdx.x] = v;
}

// ---------------------------------------------------------------------------
// Softmax over V=10000 (output), in place. One block per (t,b) row; the row
// is staged in LDS (40 KB) so global is read once + written once.
// ---------------------------------------------------------------------------
__global__ __launch_bounds__(256)
void softmax_v(float* __restrict__ out)
{
    __shared__ float buf[VOCAB];
    __shared__ float red[4];
    float* p = out + (size_t)blockIdx.x * VOCAB;
    float mx = -INFINITY;
    for (int i = threadIdx.x; i < VOCAB; i += 256) {
        float x = p[i]; buf[i] = x; mx = fmaxf(mx, x);
    }
    mx = blockReduceMax_(mx, red);
    float sm = 0.f;
    for (int i = threadIdx.x; i < VOCAB; i += 256) {
        float e = expf(buf[i] - mx); buf[i] = e; sm += e;
    }
    sm = blockReduceSum_(sm, red);
    float inv = 1.f / sm;
    for (int i = threadIdx.x; i < VOCAB; i += 256) p[i] = buf[i] * inv;
}

// ---------------------------------------------------------------------------
// Prep: combined biases (b_ih + b_hh) and zeroed barrier counters (ws is
// poisoned 0xAA before every call, so counters must be re-zeroed each call).
// ---------------------------------------------------------------------------
__global__ void prep(const float* __restrict__ bi1, const float* __restrict__ bh1,
                     const float* __restrict__ bi2, const float* __restrict__ bh2,
                     float* __restrict__ bias1, float* __restrict__ bias2,
                     unsigned* __restrict__ cnts)
{
    int i = blockIdx.x * 256 + threadIdx.x;
    if (i < G4H) { bias1[i] = bi1[i] + bh1[i]; bias2[i] = bi2[i] + bh2[i]; }
    if (i < 8) cnts[i] = 0u;
}

// ---------------------------------------------------------------------------
extern "C" void kernel_launch(void* const* d_in, const int* in_sizes, int n_in,
                              void* d_out, int out_size, void* d_ws, size_t ws_size,
                              hipStream_t stream)
{
    const float* inputs = (const float*)d_in[0];   // (T,B,E)
    const float* h0     = (const float*)d_in[1];   // (2,B,H)
    const float* c0     = (const float*)d_in[2];   // (2,B,H)
    const float* L      = (const float*)d_in[3];   // (U,B,H)
    const float* W_ih1  = (const float*)d_in[4];   // (4H,E)
    const float* W_hh1  = (const float*)d_in[5];   // (4H,H)
    const float* b_ih1  = (const float*)d_in[6];
    const float* b_hh1  = (const float*)d_in[7];
    const float* W_ih2  = (const float*)d_in[8];   // (4H,H)
    const float* W_hh2  = (const float*)d_in[9];   // (4H,H)
    const float* b_ih2  = (const float*)d_in[10];
    const float* b_hh2  = (const float*)d_in[11];
    const float* W_out  = (const float*)d_in[12];  // (V,H)
    const float* b_out  = (const float*)d_in[13];  // (V)
    float* out = (float*)d_out;                    // (T,B,V) fp32

    // Workspace layout (~59 MB total; scores aliases the dead pre-gates buf)
    float* ws    = (float*)d_ws;
    float* gates = ws;                                        // T*B*4H = 8,388,608 f
    float* h1    = gates + (size_t)T_STEPS * BATCH * G4H;     // T*B*H
    float* h2    = h1    + (size_t)T_STEPS * BATCH * HID;     // T*B*H
    float* ctx   = h2    + (size_t)T_STEPS * BATCH * HID;     // T*B*H
    float* bias1 = ctx   + (size_t)T_STEPS * BATCH * HID;     // 4H
    float* bias2 = bias1 + G4H;                               // 4H
    unsigned* cnts = (unsigned*)(bias2 + G4H);                // barrier counters
    float* scores = gates;                                    // alias (T,B,U)

    prep<<<8, 256, 0, stream>>>(b_ih1, b_hh1, b_ih2, b_hh2, bias1, bias2, cnts);

    // X1 = inputs @ W_ih1^T + (b_ih1+b_hh1)   [4096 x 2048 x 512]
    gemm_f32<true><<<dim3(G4H / 64, (T_STEPS * BATCH) / 64, 1), 256, 0, stream>>>(
        inputs, EMB, 0, W_ih1, EMB, 0, gates, G4H, 0,
        T_STEPS * BATCH, G4H, EMB, bias1);

    // Layer-1 scan -> h1_all
    lstm_scan<<<256, 256, 0, stream>>>(gates, W_hh1, h0, c0, h1, cnts + 0);

    // scores[t,b,u] = h1[t,b,:] . L[u,b,:]   batched over b (NT GEMM)
    gemm_f32<true><<<dim3(ULEN / 64, T_STEPS / 64, BATCH), 256, 0, stream>>>(
        h1, (long)BATCH * HID, HID,
        L,  (long)BATCH * HID, HID,
        scores, (long)BATCH * ULEN, ULEN,
        T_STEPS, ULEN, HID, nullptr);

    softmax_u<<<T_STEPS * BATCH, 256, 0, stream>>>(scores);

    // ctx[t,b,h] = sum_u w[t,b,u] * L[u,b,h]  batched over b (NN GEMM, K=U)
    gemm_f32<false><<<dim3(HID / 64, T_STEPS / 64, BATCH), 256, 0, stream>>>(
        scores, (long)BATCH * ULEN, ULEN,
        L,      (long)BATCH * HID,  HID,
        ctx,    (long)BATCH * HID,  HID,
        T_STEPS, HID, ULEN, nullptr);

    // X2 = ctx @ W_ih2^T + (b_ih2+b_hh2)   [4096 x 2048 x 512] (reuses gates buf)
    gemm_f32<true><<<dim3(G4H / 64, (T_STEPS * BATCH) / 64, 1), 256, 0, stream>>>(
        ctx, HID, 0, W_ih2, HID, 0, gates, G4H, 0,
        T_STEPS * BATCH, G4H, HID, bias2);

    // Layer-2 scan -> h2_all
    lstm_scan<<<256, 256, 0, stream>>>(gates, W_hh2, h0 + BATCH * HID, c0 + BATCH * HID,
                                       h2, cnts + 1);

    // logits = h2 @ W_out^T + b_out   [4096 x 10000 x 512] -> d_out
    gemm_f32<true><<<dim3(cdiv(VOCAB, 64), (T_STEPS * BATCH) / 64, 1), 256, 0, stream>>>(
        h2, HID, 0, W_out, HID, 0, out, VOCAB, 0,
        T_STEPS * BATCH, VOCAB, HID, b_out);

    softmax_v<<<T_STEPS * BATCH, 256, 0, stream>>>(out);
}

// Round 3
// 3133.503 us; speedup vs baseline: 3.7611x; 3.1321x over previous
//
#include <hip/hip_runtime.h>

// Problem constants (AttentionSpeller): T=128, B=32, E=H=512, U=1024, V=10000
#define T_STEPS 128
#define BATCH   32
#define HID     512
#define EMB     512
#define ULEN    1024
#define VOCAB   10000
#define G4H     2048   // 4*H

// Barrier region: 256 arrive words (stride 16 u32 = 64 B) + 32 go words
// (stride 64 u32 = 256 B). 6144 u32 per scan, two scans.
#define ARR_STRIDE 16
#define GO_OFF     4096
#define GO_STRIDE  64
#define BAR_WORDS  6144

static inline int cdiv(int a, int b) { return (a + b - 1) / b; }

// ---------------------------------------------------------------------------
// Generic tiled fp32 GEMM: C[M,N] = A[M,K] * op(B) (+ bias[N])
//   TRANSB=true : B is [N,K] row-major (C = A * B^T)
//   TRANSB=false: B is [K,N] row-major (C = A * B)
// Batched via blockIdx.z with element strides sA/sB/sC.
// Assumes: M % 64 == 0, K % 16 == 0. N guarded (for V=10000).
// ---------------------------------------------------------------------------
template <bool TRANSB>
__global__ __launch_bounds__(256)
void gemm_f32(const float* __restrict__ A, long lda, long sA,
              const float* __restrict__ Bm, long ldb, long sB,
              float* __restrict__ C, long ldc, long sC,
              int M, int N, int K, const float* __restrict__ bias)
{
    __shared__ float As[16][68];
    __shared__ float Bs[16][68];
    const int bz = blockIdx.z;
    A  += (size_t)bz * sA;
    Bm += (size_t)bz * sB;
    C  += (size_t)bz * sC;
    const int m0 = blockIdx.y * 64;
    const int n0 = blockIdx.x * 64;
    const int tid = threadIdx.x;
    const int tx = tid & 15, ty = tid >> 4;
    const int lr = tid >> 2;          // 0..63: tile row
    const int lk = (tid & 3) * 4;     // 0,4,8,12: k offset

    float acc[4][4] = {{0.f}};

    for (int k0 = 0; k0 < K; k0 += 16) {
        float4 av = *(const float4*)(A + (size_t)(m0 + lr) * lda + (k0 + lk));
        As[lk + 0][lr] = av.x; As[lk + 1][lr] = av.y;
        As[lk + 2][lr] = av.z; As[lk + 3][lr] = av.w;
        if (TRANSB) {
            const int nr = n0 + lr;
            float4 bv = make_float4(0.f, 0.f, 0.f, 0.f);
            if (nr < N) bv = *(const float4*)(Bm + (size_t)nr * ldb + (k0 + lk));
            Bs[lk + 0][lr] = bv.x; Bs[lk + 1][lr] = bv.y;
            Bs[lk + 2][lr] = bv.z; Bs[lk + 3][lr] = bv.w;
        } else {
            const int kr = tid >> 4;          // 0..15
            const int nc = (tid & 15) * 4;    // 0..60
            float4 bv = make_float4(0.f, 0.f, 0.f, 0.f);
            if (n0 + nc < N) bv = *(const float4*)(Bm + (size_t)(k0 + kr) * ldb + (n0 + nc));
            *(float4*)&Bs[kr][nc] = bv;
        }
        __syncthreads();
#pragma unroll
        for (int kk = 0; kk < 16; ++kk) {
            float ar[4], br[4];
#pragma unroll
            for (int i = 0; i < 4; i++) ar[i] = As[kk][ty * 4 + i];
#pragma unroll
            for (int j = 0; j < 4; j++) br[j] = Bs[kk][tx * 4 + j];
#pragma unroll
            for (int i = 0; i < 4; i++)
#pragma unroll
                for (int j = 0; j < 4; j++)
                    acc[i][j] += ar[i] * br[j];
        }
        __syncthreads();
    }
#pragma unroll
    for (int i = 0; i < 4; i++) {
        const int row = m0 + ty * 4 + i;
#pragma unroll
        for (int j = 0; j < 4; j++) {
            const int col = n0 + tx * 4 + j;
            if (col < N) {
                float v = acc[i][j];
                if (bias) v += bias[col];
                C[(size_t)row * ldc + col] = v;
            }
        }
    }
}

// ---------------------------------------------------------------------------
// Persistent LSTM scan v3 — contention-free tree barrier + cached staging.
//
// 256 blocks (1/CU), 256 threads; tid = b*8 + nl. Block bid owns h columns
// {2bid, 2bid+1} = gate columns n = g*512 + 2bid + (nl&1).
//
// v2 post-mortem: the single-counter barrier (256 same-address atomicAdds +
// 255 blocks spin-polling the same line) serialized at one coherence-point
// slice -> ~30us/step. v3:
//  - arrive: per-block flag words (64B apart, relaxed agent atomic store).
//  - block 0 aggregates (one flag per thread + __syncthreads_count),
//    releases via 32 go-words 256B apart; 8 pollers per word.
//  - h staging: PLAIN float4 loads (L1/L2-cached). Safe: h stores are
//    write-through (sc1), readers first touch an h_all[t-1] line only after
//    the barrier, 64KB slabs are line-aligned, and kernel-dispatch acquire
//    invalidates pre-kernel stale lines (same guarantee the plain gates/W
//    reads already rely on).
//  - W_hh rows (16.5KB) staged once in LDS (stride 516 -> conflict-free).
// ---------------------------------------------------------------------------
__device__ inline float sigmoidf_(float x) { return 1.f / (1.f + expf(-x)); }

__global__ __launch_bounds__(256)
void lstm_scan(const float* __restrict__ gp,    // (T*B*2048) x@W_ih^T + b_ih + b_hh
               const float* __restrict__ Whh,   // (2048 x 512) row-major
               const float* __restrict__ h0,    // (B*H) layer slice
               const float* __restrict__ c0,    // (B*H) layer slice
               float* __restrict__ h_all,       // (T*B*H) out
               unsigned* __restrict__ bar)      // zeroed barrier region
{
    __shared__ float h_lds[BATCH * HID];        // 64 KB, XOR-swizzled
    __shared__ float W_lds[8 * 516];            // 16.5 KB, padded stride
    unsigned* arrive = bar;
    unsigned* go     = bar + GO_OFF;

    const int tid  = threadIdx.x;
    const int lane = tid & 63;
    const int b    = tid >> 3;                  // 0..31
    const int nl   = tid & 7;                   // 0..7
    const int j    = nl & 1;
    const int bid  = blockIdx.x;
    const int hbase = bid * 2;
    const int swz  = (b & 7) << 2;
    const int sbase = lane & ~7;                // shuffle group base lane

    // ---- stage this block's 8 W_hh rows into LDS (once) ----
    {
        const int wrow = tid >> 5;              // 0..7
        const int wcol = (tid & 31) * 16;       // 0..496
        const float* wsrc = Whh + (size_t)((wrow >> 1) * 512 + hbase + (wrow & 1)) * HID + wcol;
        float4* wdst = (float4*)&W_lds[wrow * 516 + wcol];
#pragma unroll
        for (int i = 0; i < 4; ++i) wdst[i] = ((const float4*)wsrc)[i];
    }

    const int n = ((nl >> 1) << 9) + hbase + j; // gate column 0..2047
    const float* wrowp = &W_lds[nl * 516];

    float c_state = (nl < 2) ? c0[b * HID + hbase + j] : 0.f;

    for (int t = 0; t < T_STEPS; ++t) {
        // h-independent gate preactivation (hide under staging)
        float gval = gp[((size_t)t * BATCH + b) * G4H + n];

        // ---- stage h(t-1) -> LDS (plain cached float4 loads) ----
        const float* hsrc = (t == 0) ? h0 : (h_all + (size_t)(t - 1) * (BATCH * HID));
#pragma unroll
        for (int i = 0; i < 16; ++i) {
            const int vi = i * 256 + tid;       // float4 index 0..4095
            float4 v = *(const float4*)(hsrc + (size_t)vi * 4);
            const int bb = vi >> 7;
            const int kk = (vi & 127) * 4;
            *(float4*)&h_lds[(bb << 9) + (kk ^ ((bb & 7) << 2))] = v;
        }
        __syncthreads();

        // ---- dot: acc = gp + h(t-1) . W_row  (both operands in LDS) ----
        const float* hrow = &h_lds[b << 9];
        float s0 = 0.f, s1 = 0.f, s2 = 0.f, s3 = 0.f;
#pragma unroll 4
        for (int k = 0; k < HID; k += 8) {
            const int i1 = k ^ swz;
            float4 ha = *(const float4*)(hrow + i1);
            float4 hb = *(const float4*)(hrow + (i1 ^ 4));
            float4 wa = *(const float4*)(wrowp + k);
            float4 wb = *(const float4*)(wrowp + k + 4);
            s0 += ha.x * wa.x + ha.y * wa.y;
            s1 += ha.z * wa.z + ha.w * wa.w;
            s2 += hb.x * wb.x + hb.y * wb.y;
            s3 += hb.z * wb.z + hb.w * wb.w;
        }
        float acc = gval + ((s0 + s1) + (s2 + s3));

        // ---- cell: exchange f/g/o via shuffles; owners nl in {0,1} ----
        float fva = __shfl(acc, sbase + 2 + j);
        float gva = __shfl(acc, sbase + 4 + j);
        float ova = __shfl(acc, sbase + 6 + j);
        if (nl < 2) {
            float iv = sigmoidf_(acc);
            float fv = sigmoidf_(fva);
            float gv = tanhf(gva);
            float ov = sigmoidf_(ova);
            c_state = fv * c_state + iv * gv;
            float hn = ov * tanhf(c_state);
            // write-through store (agent scope) -> visible at coherence point
            __hip_atomic_store(h_all + ((size_t)t * BATCH + b) * HID + hbase + j,
                               hn, __ATOMIC_RELAXED, __HIP_MEMORY_SCOPE_AGENT);
        }

        // ---- grid barrier: syncthreads drains the h stores first ----
        __syncthreads();
        const unsigned want = (unsigned)(t + 1);
        if (bid == 0) {
            if (tid == 0)
                __hip_atomic_store(&arrive[0], want, __ATOMIC_RELAXED,
                                   __HIP_MEMORY_SCOPE_AGENT);
            unsigned v;
            do {
                v = __hip_atomic_load(&arrive[tid * ARR_STRIDE], __ATOMIC_RELAXED,
                                      __HIP_MEMORY_SCOPE_AGENT);
            } while (__syncthreads_count(v >= want) < 256);
            if (tid < 32)
                __hip_atomic_store(&go[tid * GO_STRIDE], want, __ATOMIC_RELAXED,
                                   __HIP_MEMORY_SCOPE_AGENT);
        } else if (tid == 0) {
            __hip_atomic_store(&arrive[bid * ARR_STRIDE], want, __ATOMIC_RELAXED,
                               __HIP_MEMORY_SCOPE_AGENT);
            unsigned g;
            do {
                __builtin_amdgcn_s_sleep(1);
                g = __hip_atomic_load(&go[(bid & 31) * GO_STRIDE], __ATOMIC_RELAXED,
                                      __HIP_MEMORY_SCOPE_AGENT);
            } while (g < want);
        }
        __syncthreads();
    }
}

// ---------------------------------------------------------------------------
// Softmax over U=1024 (attention weights), in place. One block per (t,b) row.
// ---------------------------------------------------------------------------
__device__ inline float warpReduceMax_(float v) {
#pragma unroll
    for (int o = 32; o > 0; o >>= 1) v = fmaxf(v, __shfl_xor(v, o));
    return v;
}
__device__ inline float warpReduceSum_(float v) {
#pragma unroll
    for (int o = 32; o > 0; o >>= 1) v += __shfl_xor(v, o);
    return v;
}
__device__ inline float blockReduceMax_(float v, float* red) {
    v = warpReduceMax_(v);
    if ((threadIdx.x & 63) == 0) red[threadIdx.x >> 6] = v;
    __syncthreads();
    float r = fmaxf(fmaxf(red[0], red[1]), fmaxf(red[2], red[3]));
    __syncthreads();
    return r;
}
__device__ inline float blockReduceSum_(float v, float* red) {
    v = warpReduceSum_(v);
    if ((threadIdx.x & 63) == 0) red[threadIdx.x >> 6] = v;
    __syncthreads();
    float r = (red[0] + red[1]) + (red[2] + red[3]);
    __syncthreads();
    return r;
}

__global__ __launch_bounds__(256)
void softmax_u(float* __restrict__ s)
{
    __shared__ float red[4];
    float4* p = (float4*)(s + (size_t)blockIdx.x * ULEN);
    float4 v = p[threadIdx.x];
    float mx = fmaxf(fmaxf(v.x, v.y), fmaxf(v.z, v.w));
    mx = blockReduceMax_(mx, red);
    v.x = expf(v.x - mx); v.y = expf(v.y - mx);
    v.z = expf(v.z - mx); v.w = expf(v.w - mx);
    float sm = blockReduceSum_(v.x + v.y + v.z + v.w, red);
    float inv = 1.f / sm;
    v.x *= inv; v.y *= inv; v.z *= inv; v.w *= inv;
    p[threadIdx.x] = v;
}

// ---------------------------------------------------------------------------
// Softmax over V=10000 (output), in place. One block per (t,b) row.
// ---------------------------------------------------------------------------
__global__ __launch_bounds__(256)
void softmax_v(float* __restrict__ out)
{
    __shared__ float buf[VOCAB];
    __shared__ float red[4];
    float* p = out + (size_t)blockIdx.x * VOCAB;
    float mx = -INFINITY;
    for (int i = threadIdx.x; i < VOCAB; i += 256) {
        float x = p[i]; buf[i] = x; mx = fmaxf(mx, x);
    }
    mx = blockReduceMax_(mx, red);
    float sm = 0.f;
    for (int i = threadIdx.x; i < VOCAB; i += 256) {
        float e = expf(buf[i] - mx); buf[i] = e; sm += e;
    }
    sm = blockReduceSum_(sm, red);
    float inv = 1.f / sm;
    for (int i = threadIdx.x; i < VOCAB; i += 256) p[i] = buf[i] * inv;
}

// ---------------------------------------------------------------------------
// Prep: combined biases (b_ih + b_hh) + zero the barrier flag regions
// (ws is re-poisoned 0xAA before every call). Launch with 48 blocks.
// ---------------------------------------------------------------------------
__global__ void prep(const float* __restrict__ bi1, const float* __restrict__ bh1,
                     const float* __restrict__ bi2, const float* __restrict__ bh2,
                     float* __restrict__ bias1, float* __restrict__ bias2,
                     unsigned* __restrict__ flags)
{
    int i = blockIdx.x * 256 + threadIdx.x;
    if (i < G4H) { bias1[i] = bi1[i] + bh1[i]; bias2[i] = bi2[i] + bh2[i]; }
    if (i < 2 * BAR_WORDS) flags[i] = 0u;
}

// ---------------------------------------------------------------------------
extern "C" void kernel_launch(void* const* d_in, const int* in_sizes, int n_in,
                              void* d_out, int out_size, void* d_ws, size_t ws_size,
                              hipStream_t stream)
{
    const float* inputs = (const float*)d_in[0];   // (T,B,E)
    const float* h0     = (const float*)d_in[1];   // (2,B,H)
    const float* c0     = (const float*)d_in[2];   // (2,B,H)
    const float* L      = (const float*)d_in[3];   // (U,B,H)
    const float* W_ih1  = (const float*)d_in[4];   // (4H,E)
    const float* W_hh1  = (const float*)d_in[5];   // (4H,H)
    const float* b_ih1  = (const float*)d_in[6];
    const float* b_hh1  = (const float*)d_in[7];
    const float* W_ih2  = (const float*)d_in[8];   // (4H,H)
    const float* W_hh2  = (const float*)d_in[9];   // (4H,H)
    const float* b_ih2  = (const float*)d_in[10];
    const float* b_hh2  = (const float*)d_in[11];
    const float* W_out  = (const float*)d_in[12];  // (V,H)
    const float* b_out  = (const float*)d_in[13];  // (V)
    float* out = (float*)d_out;                    // (T,B,V) fp32

    // Workspace layout (~59 MB; scores aliases the dead pre-gates buffer)
    float* ws    = (float*)d_ws;
    float* gates = ws;                                        // T*B*4H
    float* h1    = gates + (size_t)T_STEPS * BATCH * G4H;     // T*B*H
    float* h2    = h1    + (size_t)T_STEPS * BATCH * HID;     // T*B*H
    float* ctx   = h2    + (size_t)T_STEPS * BATCH * HID;     // T*B*H
    float* bias1 = ctx   + (size_t)T_STEPS * BATCH * HID;     // 4H
    float* bias2 = bias1 + G4H;                               // 4H
    unsigned* flags = (unsigned*)(bias2 + G4H);               // 2*6144 u32
    float* scores = gates;                                    // alias (T,B,U)

    prep<<<48, 256, 0, stream>>>(b_ih1, b_hh1, b_ih2, b_hh2, bias1, bias2, flags);

    // X1 = inputs @ W_ih1^T + (b_ih1+b_hh1)   [4096 x 2048 x 512]
    gemm_f32<true><<<dim3(G4H / 64, (T_STEPS * BATCH) / 64, 1), 256, 0, stream>>>(
        inputs, EMB, 0, W_ih1, EMB, 0, gates, G4H, 0,
        T_STEPS * BATCH, G4H, EMB, bias1);

    // Layer-1 scan -> h1_all
    lstm_scan<<<256, 256, 0, stream>>>(gates, W_hh1, h0, c0, h1, flags);

    // scores[t,b,u] = h1[t,b,:] . L[u,b,:]   batched over b (NT GEMM)
    gemm_f32<true><<<dim3(ULEN / 64, T_STEPS / 64, BATCH), 256, 0, stream>>>(
        h1, (long)BATCH * HID, HID,
        L,  (long)BATCH * HID, HID,
        scores, (long)BATCH * ULEN, ULEN,
        T_STEPS, ULEN, HID, nullptr);

    softmax_u<<<T_STEPS * BATCH, 256, 0, stream>>>(scores);

    // ctx[t,b,h] = sum_u w[t,b,u] * L[u,b,h]  batched over b (NN GEMM, K=U)
    gemm_f32<false><<<dim3(HID / 64, T_STEPS / 64, BATCH), 256, 0, stream>>>(
        scores, (long)BATCH * ULEN, ULEN,
        L,      (long)BATCH * HID,  HID,
        ctx,    (long)BATCH * HID,  HID,
        T_STEPS, HID, ULEN, nullptr);

    // X2 = ctx @ W_ih2^T + (b_ih2+b_hh2)   [4096 x 2048 x 512]
    gemm_f32<true><<<dim3(G4H / 64, (T_STEPS * BATCH) / 64, 1), 256, 0, stream>>>(
        ctx, HID, 0, W_ih2, HID, 0, gates, G4H, 0,
        T_STEPS * BATCH, G4H, HID, bias2);

    // Layer-2 scan -> h2_all
    lstm_scan<<<256, 256, 0, stream>>>(gates, W_hh2, h0 + BATCH * HID, c0 + BATCH * HID,
                                       h2, flags + BAR_WORDS);

    // logits = h2 @ W_out^T + b_out   [4096 x 10000 x 512] -> d_out
    gemm_f32<true><<<dim3(cdiv(VOCAB, 64), (T_STEPS * BATCH) / 64, 1), 256, 0, stream>>>(
        h2, HID, 0, W_out, HID, 0, out, VOCAB, 0,
        T_STEPS * BATCH, VOCAB, HID, b_out);

    softmax_v<<<T_STEPS * BATCH, 256, 0, stream>>>(out);
}